// Round 3
// baseline (1963.225 us; speedup 1.0000x reference)
//
#include <hip/hip_runtime.h>
#include <cstdint>
#include <cstddef>

#define NNODES 50000
#define NREL   16
#define DIM    200
#define NEDGE  400000
#define NKEY   (NREL * NNODES)      // 800000, key = dst*16 + r (dst-major!)
#define NPART  3125                 // NKEY / 256
#define WTN    208                  // padded n (13 x 16)
#define WTK    224                  // padded k (7 x 32)
#define WTSZ   (17 * WTN * WTK)
#define PERM_CAP 2048               // LDS edge cache per block (P(block deg > 2048) ~ 0)

typedef __attribute__((ext_vector_type(8))) short short8;   // 8 bf16
typedef __attribute__((ext_vector_type(4))) float floatx4;  // MFMA C/D

__device__ __forceinline__ unsigned short f2bf(float f) {
    unsigned int u = __float_as_uint(f);
    u = (u + 0x7FFFu + ((u >> 16) & 1u)) >> 16;   // RNE
    return (unsigned short)u;
}
__device__ __forceinline__ float bf2f(unsigned short h) {
    return __uint_as_float(((unsigned int)h) << 16);
}

// ---------- preprocessing: counting sort of edges by key = dst*16 + r ----------

__global__ void count_kernel(const int* __restrict__ ei, const int* __restrict__ et,
                             int* __restrict__ cnt) {
    int e = blockIdx.x * 256 + threadIdx.x;
    if (e < NEDGE) atomicAdd(&cnt[ei[NEDGE + e] * NREL + et[e]], 1);
}

__global__ void scan1_kernel(const int* __restrict__ cnt, int* __restrict__ rp,
                             int* __restrict__ part) {
    __shared__ int sc[256];
    int b = blockIdx.x, t = threadIdx.x, i = b * 256 + t;
    int v = cnt[i];
    sc[t] = v; __syncthreads();
    for (int off = 1; off < 256; off <<= 1) {
        int x = (t >= off) ? sc[t - off] : 0;
        __syncthreads();
        sc[t] += x;
        __syncthreads();
    }
    int incl = sc[t];
    rp[i] = incl - v;
    if (t == 255) part[b] = incl;
}

__global__ void scan2_kernel(int* __restrict__ p) {
    __shared__ int sc[256];
    __shared__ int carry_s;
    int t = threadIdx.x;
    if (t == 0) carry_s = 0;
    __syncthreads();
    for (int base = 0; base < NPART; base += 256) {
        int i = base + t;
        int v = (i < NPART) ? p[i] : 0;
        sc[t] = v; __syncthreads();
        for (int off = 1; off < 256; off <<= 1) {
            int x = (t >= off) ? sc[t - off] : 0;
            __syncthreads();
            sc[t] += x;
            __syncthreads();
        }
        int incl = sc[t];
        int carry = carry_s;
        if (i < NPART) p[i] = carry + incl - v;
        __syncthreads();
        if (t == 255) carry_s = carry + incl;
        __syncthreads();
    }
    if (t == 0) p[NPART] = carry_s;   // == NEDGE
}

__global__ void scan3_kernel(int* __restrict__ rp, int* __restrict__ cursor,
                             const int* __restrict__ part) {
    int i = blockIdx.x * 256 + threadIdx.x;
    if (i < NKEY) {
        int v = rp[i] + part[i >> 8];
        rp[i] = v;
        cursor[i] = v;
    } else if (i == NKEY) {
        rp[i] = part[NPART];
    }
}

// perm[pos] = src node of the edge
__global__ void scatter_kernel(const int* __restrict__ ei, const int* __restrict__ et,
                               int* __restrict__ cursor, int* __restrict__ perm) {
    int e = blockIdx.x * 256 + threadIdx.x;
    if (e < NEDGE) {
        int key = ei[NEDGE + e] * NREL + et[e];
        int pos = atomicAdd(&cursor[key], 1);
        perm[pos] = ei[e];
    }
}

// ---------- W^T prep: WT[r][n][k] bf16, zero-padded; r==16 is root ----------
__global__ void wt_kernel(const float* __restrict__ W, const float* __restrict__ root,
                          unsigned short* __restrict__ WT) {
    int idx = blockIdx.x * 256 + threadIdx.x;
    if (idx >= WTSZ) return;
    int r = idx / (WTN * WTK);
    int rem = idx - r * (WTN * WTK);
    int n = rem / WTK;
    int k = rem - n * WTK;
    float v = 0.f;
    if (n < DIM && k < DIM)
        v = (r < 16) ? W[((size_t)r * DIM + k) * DIM + n] : root[(size_t)k * DIM + n];
    WT[idx] = f2bf(v);
}

// ---------- fused layer ----------
// Block: 64 dst rows. LDS-cached rp slice + perm slice (dst-major sort makes both
// contiguous). No barriers in the chunk loop: wave w exclusively owns As rows
// [w*16, w*16+16). First-edge gathers issued 4 rows at a time (independent loads).
template<bool SRC_F32, bool OUT_RELU_BF16>
__global__ __launch_bounds__(256) void fused_kernel(
        const void* __restrict__ srcv, const unsigned short* __restrict__ WT,
        const int* __restrict__ rp, const int* __restrict__ perm,
        const float* __restrict__ bias, void* __restrict__ outv) {
    __shared__ __align__(16) char As[25664];   // 64 rows x 400 B bf16 + 64 B slack
    __shared__ int s_rp[1025];
    __shared__ int s_perm[PERM_CAP];
    const int t = threadIdx.x;
    const int w = t >> 6;
    const int lane = t & 63;
    const int quad = lane >> 4;
    const int mn = lane & 15;
    const int v0 = blockIdx.x * 64;
    const int kbase = v0 * NREL;
    const bool colok = (lane < 50);

    for (int i = t; i < 1025; i += 256) {
        int gk = kbase + i;
        s_rp[i] = (gk <= NKEY) ? rp[gk] : NEDGE;
    }
    if (t < 16) *(unsigned int*)(As + 25600 + t * 4) = 0u;
    __syncthreads();
    const int eStart = s_rp[0];
    const int nE = s_rp[1024] - eStart;
    for (int i = t; i < nE && i < PERM_CAP; i += 256) s_perm[i] = perm[eStart + i];
    __syncthreads();

    const float* srcf = (const float*)srcv;
    const unsigned short* srcb = (const unsigned short*)srcv;

    floatx4 acc[13];
    #pragma unroll
    for (int i = 0; i < 13; ++i) acc[i] = (floatx4){0.f, 0.f, 0.f, 0.f};

    auto pread = [&](int j) -> int {          // j = global edge position
        int idx = j - eStart;
        return (idx < PERM_CAP) ? s_perm[idx] : perm[j];
    };
    auto ldrow = [&](int node) -> float4 {    // 16B-per-lane row gather
        if (SRC_F32) {
            return *(const float4*)(srcf + (size_t)node * DIM + lane * 4);
        } else {
            ushort4 u = *(const ushort4*)(srcb + (size_t)node * DIM + lane * 4);
            return make_float4(bf2f(u.x), bf2f(u.y), bf2f(u.z), bf2f(u.w));
        }
    };
    auto do_mfma = [&](int r) {
        const char* WTr = (const char*)(WT + (size_t)r * (WTN * WTK));
        const char* arow = As + ((w << 4) + mn) * 400 + quad * 16;
        const char* brow = WTr + (size_t)mn * (WTK * 2) + quad * 16;
        for (int ks = 0; ks < 7; ++ks) {
            const short8 af = *(const short8*)(arow + ks * 64);
            #pragma unroll
            for (int nt = 0; nt < 13; ++nt) {
                const short8 bf = *(const short8*)(brow + ks * 64 + nt * (16 * WTK * 2));
                acc[nt] = __builtin_amdgcn_mfma_f32_16x16x32_bf16(af, bf, acc[nt], 0, 0, 0);
            }
        }
    };

    for (int r = 0; r < NREL; ++r) {
        // lane i (i<16) holds bounds of row i of this wave's 16 rows
        int sB = 0, eB = 0;
        if (lane < 16) {
            int kk = ((w << 4) + lane) * NREL + r;
            sB = s_rp[kk];
            eB = s_rp[kk + 1];
        }
        #pragma unroll
        for (int g = 0; g < 4; ++g) {
            int s4[4], e4[4];
            float4 q[4];
            #pragma unroll
            for (int i = 0; i < 4; ++i) {
                s4[i] = __builtin_amdgcn_readlane(sB, g * 4 + i);
                e4[i] = __builtin_amdgcn_readlane(eB, g * 4 + i);
            }
            // issue first-edge gathers for 4 rows back-to-back (independent)
            #pragma unroll
            for (int i = 0; i < 4; ++i) {
                q[i] = make_float4(0.f, 0.f, 0.f, 0.f);
                if (e4[i] > s4[i] && colok) q[i] = ldrow(pread(s4[i]));
            }
            // accumulate + rare extra edges + pack
            #pragma unroll
            for (int i = 0; i < 4; ++i) {
                int m = (w << 4) + g * 4 + i;
                float a0 = q[i].x, a1 = q[i].y, a2 = q[i].z, a3 = q[i].w;
                int cnt = e4[i] - s4[i];
                for (int j = s4[i] + 1; j < e4[i]; ++j) {
                    if (colok) {
                        float4 qq = ldrow(pread(j));
                        a0 += qq.x; a1 += qq.y; a2 += qq.z; a3 += qq.w;
                    }
                }
                float sc = (cnt > 0) ? 1.f / (float)cnt : 0.f;
                a0 *= sc; a1 *= sc; a2 *= sc; a3 *= sc;
                if (colok) {
                    ushort4 pk;
                    pk.x = f2bf(a0); pk.y = f2bf(a1); pk.z = f2bf(a2); pk.w = f2bf(a3);
                    *(ushort4*)(As + m * 400 + lane * 8) = pk;
                }
            }
        }
        do_mfma(r);
    }

    // root chunk (r == 16): A = x rows directly; 16 independent loads pipeline
    {
        #pragma unroll
        for (int i = 0; i < 16; ++i) {
            int m = (w << 4) + i;
            int v = v0 + m;
            float4 qv = make_float4(0.f, 0.f, 0.f, 0.f);
            if (v < NNODES && colok) qv = ldrow(v);
            if (colok) {
                ushort4 pk;
                pk.x = f2bf(qv.x); pk.y = f2bf(qv.y); pk.z = f2bf(qv.z); pk.w = f2bf(qv.w);
                *(ushort4*)(As + m * 400 + lane * 8) = pk;
            }
        }
        do_mfma(16);
    }

    // epilogue: C row = quad*4 + i, col = nt*16 + mn
    float* outf = (float*)outv;
    unsigned short* outb = (unsigned short*)outv;
    #pragma unroll
    for (int nt = 0; nt < 13; ++nt) {
        const int col = nt * 16 + mn;
        if (col < DIM) {
            const float bv = bias[col];
            #pragma unroll
            for (int i = 0; i < 4; ++i) {
                const int v = v0 + (w << 4) + quad * 4 + i;
                if (v < NNODES) {
                    float x = acc[nt][i] + bv;
                    if (OUT_RELU_BF16) {
                        x = fmaxf(x, 0.f);
                        outb[(size_t)v * DIM + col] = f2bf(x);
                    } else {
                        outf[(size_t)v * DIM + col] = x;
                    }
                }
            }
        }
    }
}

// ---------- launch ----------

extern "C" void kernel_launch(void* const* d_in, const int* in_sizes, int n_in,
                              void* d_out, int out_size, void* d_ws, size_t ws_size,
                              hipStream_t stream) {
    const int*   edge_index = (const int*)d_in[0];
    const int*   edge_type  = (const int*)d_in[1];
    const float* emb   = (const float*)d_in[2];
    const float* W1    = (const float*)d_in[3];
    const float* root1 = (const float*)d_in[4];
    const float* b1    = (const float*)d_in[5];
    const float* W2    = (const float*)d_in[6];
    const float* root2 = (const float*)d_in[7];
    const float* b2    = (const float*)d_in[8];
    float* out = (float*)d_out;

    char* ws = (char*)d_ws;
    int*            cnt    = (int*)(ws);
    int*            rp     = (int*)(ws + 3200000);
    int*            cursor = (int*)(ws + 6400128);
    int*            part   = (int*)(ws + 9600128);
    int*            perm   = (int*)(ws + 9612672);
    unsigned short* hbf    = (unsigned short*)(ws + 11212672);
    unsigned short* WT1    = (unsigned short*)(ws + 31212672);
    unsigned short* WT2    = (unsigned short*)(ws + 32796800);

    // counting sort by key = dst*16 + r
    hipMemsetAsync(cnt, 0, (size_t)NKEY * sizeof(int), stream);
    count_kernel<<<(NEDGE + 255) / 256, 256, 0, stream>>>(edge_index, edge_type, cnt);
    scan1_kernel<<<NPART, 256, 0, stream>>>(cnt, rp, part);
    scan2_kernel<<<1, 256, 0, stream>>>(part);
    scan3_kernel<<<(NKEY + 256) / 256 + 1, 256, 0, stream>>>(rp, cursor, part);
    scatter_kernel<<<(NEDGE + 255) / 256, 256, 0, stream>>>(edge_index, edge_type, cursor, perm);

    wt_kernel<<<(WTSZ + 255) / 256, 256, 0, stream>>>(W1, root1, WT1);
    wt_kernel<<<(WTSZ + 255) / 256, 256, 0, stream>>>(W2, root2, WT2);

    const int nblk = (NNODES + 63) / 64;   // 782
    fused_kernel<true, true><<<nblk, 256, 0, stream>>>(emb, WT1, rp, perm, b1, hbf);
    fused_kernel<false, false><<<nblk, 256, 0, stream>>>(hbf, WT2, rp, perm, b2, out);
}